// Round 7
// baseline (111.194 us; speedup 1.0000x reference)
//
#include <hip/hip_runtime.h>
#include <math.h>

#define BW 4096
#define DD 64
#define HH 256

typedef __bf16 bf16x8 __attribute__((ext_vector_type(8)));
typedef float  f32x4  __attribute__((ext_vector_type(4)));
typedef unsigned short u16x8 __attribute__((ext_vector_type(8)));

// ws layout (ushort units), fragments for mfma_f32_16x16x32_bf16:
// WIN: A-frags of w_inT, standard k-bij (k=8g+j).  frag(kin,ht): kin 0..1, ht 0..15
// WA1: B-frags, HID k-bij  k=16*(j>>2)+4g+(j&3).  frag(kt,ct):  kt 0..7,  ct 0..3
// WV1: B-frags, HID k-bij.                         frag(kt,ct):  kt 0..7,  ct 0..15
// WV2: B-frags, standard k-bij (k=8g+j).           frag(kt,ct):  kt 0..7,  ct 0..15
#define WIN_OFF 0
#define WA1_OFF 16384
#define WV1_OFF 32768
#define WV2_OFF 98304
// total (2048+2048+8192+8192) chunks * 16B = 327680 bytes of ws

__device__ __forceinline__ unsigned short to_bf16u(float f) {
    union { __bf16 b; unsigned short u; } cv;
    cv.b = (__bf16)f;           // RNE
    return cv.u;
}

// tanh-form GELU via sigmoid: x * sigmoid(1.59577x + 0.0713548x^3)
// |err vs exact-erf gelu| <= ~5e-4 abs; 5 VALU + 2 transcendental.
__device__ __forceinline__ float gelu_fast(float x) {
    float x2 = x * x;
    float z  = x * __builtin_fmaf(-0.10294344f, x2, -2.3022082f);
    float e  = __builtin_amdgcn_exp2f(z);
    return x * __builtin_amdgcn_rcpf(1.0f + e);
}

__device__ __forceinline__ f32x4 mfma16(bf16x8 a, bf16x8 b, f32x4 c) {
    return __builtin_amdgcn_mfma_f32_16x16x32_bf16(a, b, c, 0, 0, 0);
}

// ---------------- weight pre-pack ----------------
__global__ void pack_weights(const float* __restrict__ w_in,
                             const float* __restrict__ w_a1,
                             const float* __restrict__ w_v1,
                             const float* __restrict__ w_v2,
                             unsigned short* __restrict__ ws) {
    int t = blockIdx.x * 256 + threadIdx.x;   // chunk id, 20480 total
    if (t >= 20480) return;
    int lane = t & 63;
    int g = lane >> 4, li = lane & 15;
    u16x8 v;
    if (t < 2048) {
        int fr = t >> 6;                      // 0..31
        int kin = fr >> 4, ht = fr & 15;
        #pragma unroll
        for (int j = 0; j < 8; ++j) {
            int k = kin * 32 + 8 * g + j;
            v[j] = to_bf16u(w_in[(size_t)k * 256 + 16 * ht + li]);
        }
        *(u16x8*)(ws + WIN_OFF + (size_t)t * 8) = v;
    } else if (t < 4096) {
        int c = t - 2048;
        int fr = c >> 6;                      // 0..31
        int kt = fr >> 2, ct = fr & 3;
        #pragma unroll
        for (int j = 0; j < 8; ++j) {
            int k = kt * 32 + 16 * (j >> 2) + 4 * g + (j & 3);
            v[j] = to_bf16u(w_a1[(size_t)k * 64 + ct * 16 + li]);
        }
        *(u16x8*)(ws + WA1_OFF + (size_t)c * 8) = v;
    } else if (t < 12288) {
        int c = t - 4096;
        int fr = c >> 6;                      // 0..127
        int kt = fr >> 4, ct = fr & 15;
        #pragma unroll
        for (int j = 0; j < 8; ++j) {
            int k = kt * 32 + 16 * (j >> 2) + 4 * g + (j & 3);
            v[j] = to_bf16u(w_v1[(size_t)k * 256 + ct * 16 + li]);
        }
        *(u16x8*)(ws + WV1_OFF + (size_t)c * 8) = v;
    } else {
        int c = t - 12288;
        int fr = c >> 6;                      // 0..127
        int kt = fr >> 4, ct = fr & 15;
        #pragma unroll
        for (int j = 0; j < 8; ++j) {
            int k = kt * 32 + 8 * g + j;      // standard bijection (matches r A-frag)
            v[j] = to_bf16u(w_v2[(size_t)k * 256 + ct * 16 + li]);
        }
        *(u16x8*)(ws + WV2_OFF + (size_t)c * 8) = v;
    }
}

// ---------------- main fused kernel: one block per (b,w) position ----------------
__global__ __launch_bounds__(256, 4)
void dist_attn_kernel(const int*   __restrict__ a1,
                      const int*   __restrict__ a2,
                      const float* __restrict__ dist,
                      const int*   __restrict__ mask,
                      const float* __restrict__ table,   // [101][32] f32
                      const float* __restrict__ w_in,    // [65][256] f32 (row 64 used)
                      const float* __restrict__ b_in,
                      const float* __restrict__ b_a1,
                      const float* __restrict__ w_a2,
                      const float* __restrict__ b_a2,
                      const float* __restrict__ b_v1,
                      const float* __restrict__ b_v2,
                      const float* __restrict__ fb,
                      const unsigned short* __restrict__ ws,
                      float*       __restrict__ out) {
    // hidfrag[dt][kt][lane][j] = hid[d=16dt+(lane&15)][h=kt*32 + 16*(j>>2)+4*(lane>>4)+(j&3)]
    __shared__ __align__(16) unsigned short hidfrag[4][8][64][8];  // 32768 B
    __shared__ __align__(16) float scorep[256];                    // 1024 B
    __shared__ __align__(16) float attn_s[256];                    // 1024 B (per-wave copies)
    __shared__ __align__(16) unsigned short r_bf[256];             // 512 B

    const int tid = threadIdx.x;
    const int l   = tid & 63;
    const int w   = tid >> 6;
    const int g   = l >> 4;
    const int li  = l & 15;
    const int blk = blockIdx.x;
    const long base = (long)blk * DD;

    // ---- P1: comb B-frags direct from global (table is L1-hot), then
    //      hidT = w_inT @ combT with C preloaded as dm*w64+b_in, gelu -> hidfrag ----
    {
        bf16x8 cb[4][2];
        float  dmv[4];
        #pragma unroll
        for (int dt = 0; dt < 4; ++dt) {
            const int i1 = a1[base + 16 * dt + li];
            const int i2 = a2[base + 16 * dt + li];
            const int m  = mask[base + 16 * dt + li];
            dmv[dt] = m ? dist[base + 16 * dt + li] : 0.0f;
            const float* s1 = table + (size_t)i1 * 32 + 8 * g;
            const float* s2 = table + (size_t)i2 * 32 + 8 * g;
            f32x4 v0 = *(const f32x4*)s1;
            f32x4 v1 = *(const f32x4*)(s1 + 4);
            f32x4 v2 = *(const f32x4*)s2;
            f32x4 v3 = *(const f32x4*)(s2 + 4);
            #pragma unroll
            for (int j = 0; j < 4; ++j) {
                cb[dt][0][j]     = (__bf16)v0[j];
                cb[dt][0][j + 4] = (__bf16)v1[j];
                cb[dt][1][j]     = (__bf16)v2[j];
                cb[dt][1][j + 4] = (__bf16)v3[j];
            }
        }
        #pragma unroll
        for (int hp = 0; hp < 2; ++hp) {          // own k-tile: kt = 2w+hp
            bf16x8 pend[4];
            #pragma unroll
            for (int b = 0; b < 2; ++b) {
                const int ht = 4 * w + 2 * hp + b;
                bf16x8 af0 = *(const bf16x8*)(ws + WIN_OFF + ((size_t)(0 * 16 + ht) * 64 + l) * 8);
                bf16x8 af1 = *(const bf16x8*)(ws + WIN_OFF + ((size_t)(1 * 16 + ht) * 64 + l) * 8);
                f32x4 w64v = *(const f32x4*)&w_in[64 * 256 + 16 * ht + 4 * g];
                f32x4 binv = *(const f32x4*)&b_in[16 * ht + 4 * g];
                #pragma unroll
                for (int dt = 0; dt < 4; ++dt) {
                    f32x4 acc;
                    #pragma unroll
                    for (int p = 0; p < 4; ++p)
                        acc[p] = __builtin_fmaf(dmv[dt], w64v[p], binv[p]);
                    acc = mfma16(af0, cb[dt][0], acc);
                    acc = mfma16(af1, cb[dt][1], acc);
                    #pragma unroll
                    for (int p = 0; p < 4; ++p)
                        pend[dt][4 * b + p] = (__bf16)gelu_fast(acc[p]);
                }
            }
            #pragma unroll
            for (int dt = 0; dt < 4; ++dt)
                *(bf16x8*)&hidfrag[dt][2 * w + hp][l][0] = pend[dt];
        }
    }
    __syncthreads();

    // ---- P2: score partials (wave w -> attn-hidden cols 16w..16w+15), B-frags preloaded ----
    {
        bf16x8 ba[8];
        #pragma unroll
        for (int kt = 0; kt < 8; ++kt)
            ba[kt] = *(const bf16x8*)(ws + WA1_OFF + ((size_t)(kt * 4 + w) * 64 + l) * 8);
        f32x4 acc2[4];
        #pragma unroll
        for (int rt = 0; rt < 4; ++rt) acc2[rt] = (f32x4){0.f, 0.f, 0.f, 0.f};
        #pragma unroll
        for (int kt = 0; kt < 8; ++kt) {
            #pragma unroll
            for (int rt = 0; rt < 4; ++rt) {
                bf16x8 a = *(const bf16x8*)&hidfrag[rt][kt][l][0];
                acc2[rt] = mfma16(a, ba[kt], acc2[rt]);
            }
        }
        const float ba1 = b_a1[16 * w + li];
        const float wa2 = w_a2[16 * w + li];
        #pragma unroll
        for (int rt = 0; rt < 4; ++rt) {
            float s[4];
            #pragma unroll
            for (int p = 0; p < 4; ++p) s[p] = gelu_fast(acc2[rt][p] + ba1) * wa2;
            #pragma unroll
            for (int off = 1; off <= 8; off <<= 1)
                #pragma unroll
                for (int p = 0; p < 4; ++p) s[p] += __shfl_xor(s[p], off, 64);
            if (li == 0) {
                f32x4 sv; sv[0] = s[0]; sv[1] = s[1]; sv[2] = s[2]; sv[3] = s[3];
                *(f32x4*)&scorep[w * 64 + 16 * rt + 4 * g] = sv;
            }
        }
    }
    __syncthreads();

    // ---- P3: softmax, redundant per wave (no extra barrier) ----
    {
        const int m = mask[base + l];
        float sc = scorep[l] + scorep[64 + l] + scorep[128 + l] + scorep[192 + l] + b_a2[0];
        if (!m) sc = -10000.0f;
        float mx = sc;
        #pragma unroll
        for (int off = 32; off; off >>= 1) mx = fmaxf(mx, __shfl_xor(mx, off, 64));
        float p = __expf(sc - mx);
        float sm = p;
        #pragma unroll
        for (int off = 32; off; off >>= 1) sm += __shfl_xor(sm, off, 64);
        attn_s[w * 64 + l] = p / sm;
    }
    // same-wave LDS RAW -> ordered by lgkmcnt, no __syncthreads needed

    // ---- P4: r[c] = sum_d attn[d]*gelu(hid@w_v1 + b_v1)[d][c]  (wave w -> cols 64w..) ----
    // ct in 2 passes of 2 to cap live accumulators at 32 (no spill).
    {
        f32x4 av[4];
        #pragma unroll
        for (int rt = 0; rt < 4; ++rt) av[rt] = *(const f32x4*)&attn_s[w * 64 + 16 * rt + 4 * g];
        #pragma unroll
        for (int half = 0; half < 2; ++half) {
            f32x4 acc3[2][4];   // [c2][rt]
            #pragma unroll
            for (int c2 = 0; c2 < 2; ++c2)
                #pragma unroll
                for (int rt = 0; rt < 4; ++rt) acc3[c2][rt] = (f32x4){0.f, 0.f, 0.f, 0.f};
            #pragma unroll
            for (int kt = 0; kt < 8; ++kt) {
                bf16x8 b0 = *(const bf16x8*)(ws + WV1_OFF + ((size_t)(kt * 16 + 4 * w + 2 * half + 0) * 64 + l) * 8);
                bf16x8 b1 = *(const bf16x8*)(ws + WV1_OFF + ((size_t)(kt * 16 + 4 * w + 2 * half + 1) * 64 + l) * 8);
                bf16x8 a[4];
                #pragma unroll
                for (int rt = 0; rt < 4; ++rt) a[rt] = *(const bf16x8*)&hidfrag[rt][kt][l][0];
                #pragma unroll
                for (int rt = 0; rt < 4; ++rt) {
                    acc3[0][rt] = mfma16(a[rt], b0, acc3[0][rt]);
                    acc3[1][rt] = mfma16(a[rt], b1, acc3[1][rt]);
                }
            }
            #pragma unroll
            for (int c2 = 0; c2 < 2; ++c2) {
                const int ct = 2 * half + c2;
                const int c = 64 * w + 16 * ct + li;
                const float bv = b_v1[c];
                float val = 0.f;
                #pragma unroll
                for (int rt = 0; rt < 4; ++rt)
                    #pragma unroll
                    for (int p = 0; p < 4; ++p)
                        val += av[rt][p] * gelu_fast(acc3[c2][rt][p] + bv);
                val += __shfl_xor(val, 16, 64);
                val += __shfl_xor(val, 32, 64);
                if (g == 0) r_bf[c] = to_bf16u(val);
            }
        }
    }
    __syncthreads();

    // ---- P5: out = r @ w_v2 via MFMA (r broadcast to all 16 A-rows), full K per wave ----
    {
        const int anyv = __any(mask[base + l] != 0);
        f32x4 acc[4];
        #pragma unroll
        for (int ct = 0; ct < 4; ++ct) acc[ct] = (f32x4){0.f, 0.f, 0.f, 0.f};
        #pragma unroll
        for (int kt = 0; kt < 8; ++kt) {
            bf16x8 a = *(const bf16x8*)&r_bf[kt * 32 + 8 * g];   // same for all li -> broadcast
            #pragma unroll
            for (int ct = 0; ct < 4; ++ct) {
                bf16x8 b = *(const bf16x8*)(ws + WV2_OFF + ((size_t)(kt * 16 + 4 * w + ct) * 64 + l) * 8);
                acc[ct] = mfma16(a, b, acc[ct]);
            }
        }
        if (g == 0) {
            #pragma unroll
            for (int ct = 0; ct < 4; ++ct) {
                const int c = 16 * (4 * w + ct) + li;
                float o = acc[ct][0] + b_v2[c];
                if (!anyv) o = fb[c];
                out[(size_t)blk * HH + c] = o;
            }
        }
    }
}

extern "C" void kernel_launch(void* const* d_in, const int* in_sizes, int n_in,
                              void* d_out, int out_size, void* d_ws, size_t ws_size,
                              hipStream_t stream) {
    const int*   a1    = (const int*)  d_in[0];
    const int*   a2    = (const int*)  d_in[1];
    const float* dist  = (const float*)d_in[2];
    const int*   mask  = (const int*)  d_in[3];
    const float* table = (const float*)d_in[4];
    const float* w_in  = (const float*)d_in[5];
    const float* b_in  = (const float*)d_in[6];
    const float* w_a1  = (const float*)d_in[7];
    const float* b_a1  = (const float*)d_in[8];
    const float* w_a2  = (const float*)d_in[9];
    const float* b_a2  = (const float*)d_in[10];
    const float* w_v1  = (const float*)d_in[11];
    const float* b_v1  = (const float*)d_in[12];
    const float* w_v2  = (const float*)d_in[13];
    const float* b_v2  = (const float*)d_in[14];
    const float* fb    = (const float*)d_in[15];
    float* out = (float*)d_out;
    unsigned short* ws = (unsigned short*)d_ws;

    pack_weights<<<80, 256, 0, stream>>>(w_in, w_a1, w_v1, w_v2, ws);
    dist_attn_kernel<<<BW, 256, 0, stream>>>(a1, a2, dist, mask, table,
                                             w_in, b_in, b_a1, w_a2, b_a2,
                                             b_v1, b_v2, fb, ws, out);
}

// Round 8
// 100.699 us; speedup vs baseline: 1.1042x; 1.1042x over previous
//
#include <hip/hip_runtime.h>
#include <math.h>

#define BW 4096
#define DD 64
#define HH 256

typedef __bf16 bf16x8 __attribute__((ext_vector_type(8)));
typedef float  f32x4  __attribute__((ext_vector_type(4)));
typedef unsigned short u16x8 __attribute__((ext_vector_type(8)));

// ws layout (ushort units), fragments for mfma_f32_16x16x32_bf16:
// WIN: A-frags of w_inT, standard k-bij (k=8g+j).  frag(kin,ht): kin 0..1, ht 0..15
// WA1: B-frags, HID k-bij  k=16*(j>>2)+4g+(j&3).  frag(kt,ct):  kt 0..7,  ct 0..3
// WV1: B-frags, HID k-bij.                         frag(kt,ct):  kt 0..7,  ct 0..15
// WV2: B-frags, standard k-bij (k=8g+j).           frag(kt,ct):  kt 0..7,  ct 0..15
#define WIN_OFF 0
#define WA1_OFF 16384
#define WV1_OFF 32768
#define WV2_OFF 98304
// total (2048+2048+8192+8192) chunks * 16B = 327680 bytes of ws

__device__ __forceinline__ unsigned short to_bf16u(float f) {
    union { __bf16 b; unsigned short u; } cv;
    cv.b = (__bf16)f;           // RNE
    return cv.u;
}

// tanh-form GELU via sigmoid: x * sigmoid(1.59577x + 0.0713548x^3)
// |err vs exact-erf gelu| <= ~5e-4 abs; 5 VALU + 2 transcendental.
__device__ __forceinline__ float gelu_fast(float x) {
    float x2 = x * x;
    float z  = x * __builtin_fmaf(-0.10294344f, x2, -2.3022082f);
    float e  = __builtin_amdgcn_exp2f(z);
    return x * __builtin_amdgcn_rcpf(1.0f + e);
}

__device__ __forceinline__ f32x4 mfma16(bf16x8 a, bf16x8 b, f32x4 c) {
    return __builtin_amdgcn_mfma_f32_16x16x32_bf16(a, b, c, 0, 0, 0);
}

// ---------------- weight pre-pack ----------------
__global__ void pack_weights(const float* __restrict__ w_in,
                             const float* __restrict__ w_a1,
                             const float* __restrict__ w_v1,
                             const float* __restrict__ w_v2,
                             unsigned short* __restrict__ ws) {
    int t = blockIdx.x * 256 + threadIdx.x;   // chunk id, 20480 total
    if (t >= 20480) return;
    int lane = t & 63;
    int g = lane >> 4, li = lane & 15;
    u16x8 v;
    if (t < 2048) {
        int fr = t >> 6;                      // 0..31
        int kin = fr >> 4, ht = fr & 15;
        #pragma unroll
        for (int j = 0; j < 8; ++j) {
            int k = kin * 32 + 8 * g + j;
            v[j] = to_bf16u(w_in[(size_t)k * 256 + 16 * ht + li]);
        }
        *(u16x8*)(ws + WIN_OFF + (size_t)t * 8) = v;
    } else if (t < 4096) {
        int c = t - 2048;
        int fr = c >> 6;                      // 0..31
        int kt = fr >> 2, ct = fr & 3;
        #pragma unroll
        for (int j = 0; j < 8; ++j) {
            int k = kt * 32 + 16 * (j >> 2) + 4 * g + (j & 3);
            v[j] = to_bf16u(w_a1[(size_t)k * 64 + ct * 16 + li]);
        }
        *(u16x8*)(ws + WA1_OFF + (size_t)c * 8) = v;
    } else if (t < 12288) {
        int c = t - 4096;
        int fr = c >> 6;                      // 0..127
        int kt = fr >> 4, ct = fr & 15;
        #pragma unroll
        for (int j = 0; j < 8; ++j) {
            int k = kt * 32 + 16 * (j >> 2) + 4 * g + (j & 3);
            v[j] = to_bf16u(w_v1[(size_t)k * 256 + ct * 16 + li]);
        }
        *(u16x8*)(ws + WV1_OFF + (size_t)c * 8) = v;
    } else {
        int c = t - 12288;
        int fr = c >> 6;                      // 0..127
        int kt = fr >> 4, ct = fr & 15;
        #pragma unroll
        for (int j = 0; j < 8; ++j) {
            int k = kt * 32 + 8 * g + j;      // standard bijection (matches r A-frag)
            v[j] = to_bf16u(w_v2[(size_t)k * 256 + ct * 16 + li]);
        }
        *(u16x8*)(ws + WV2_OFF + (size_t)c * 8) = v;
    }
}

// ---------------- main fused kernel: one block per (b,w) position ----------------
__global__ __launch_bounds__(256, 4)
void dist_attn_kernel(const int*   __restrict__ a1,
                      const int*   __restrict__ a2,
                      const float* __restrict__ dist,
                      const int*   __restrict__ mask,
                      const float* __restrict__ table,   // [101][32] f32
                      const float* __restrict__ w_in,    // [65][256] f32 (row 64 used)
                      const float* __restrict__ b_in,
                      const float* __restrict__ b_a1,
                      const float* __restrict__ w_a2,
                      const float* __restrict__ b_a2,
                      const float* __restrict__ b_v1,
                      const float* __restrict__ b_v2,
                      const float* __restrict__ fb,
                      const unsigned short* __restrict__ ws,
                      float*       __restrict__ out) {
    // sU: P0-P1: comb B-frags (8192B). P2+: scorep @0 (1KB) | attn @1024 ([4][64] f32) | r_bf @2048 (512B)
    __shared__ __align__(16) unsigned char sU[8192];
    // hidfrag[dt][kt][lane][j] = hid[d=16dt+(lane&15)][h=kt*32 + 16*(j>>2)+4*(lane>>4)+(j&3)]
    __shared__ __align__(16) unsigned short hidfrag[4][8][64][8];  // 32768B; total 40960B

    unsigned short (*combfrag)[2][64][8] = (unsigned short (*)[2][64][8])sU;
    float*          scorep = (float*)sU;               // [4][64]
    float*          attn_s = (float*)(sU + 1024);      // [4][64] per-wave copies
    unsigned short* r_bf   = (unsigned short*)(sU + 2048);  // [256] bf16

    const int tid = threadIdx.x;
    const int l   = tid & 63;
    const int w   = tid >> 6;
    const int g   = l >> 4;
    const int li  = l & 15;
    const int blk = blockIdx.x;
    const long base = (long)blk * DD;

    // ---- P0: wave w builds comb B-frag tile dt=w (pairs d = 16w+li) ----
    {
        const int i1 = a1[base + 16 * w + li];
        const int i2 = a2[base + 16 * w + li];
        #pragma unroll
        for (int ks = 0; ks < 2; ++ks) {
            const int idx = ks ? i2 : i1;
            const float* srcp = table + (size_t)idx * 32 + 8 * g;
            f32x4 v0 = *(const f32x4*)srcp;
            f32x4 v1 = *(const f32x4*)(srcp + 4);
            u16x8 u;
            #pragma unroll
            for (int j = 0; j < 4; ++j) { u[j] = to_bf16u(v0[j]); u[j + 4] = to_bf16u(v1[j]); }
            *(u16x8*)&combfrag[w][ks][l][0] = u;
        }
    }
    __syncthreads();

    // ---- P1: hidT = w_inT @ combT, C preloaded with dm*w64 + b_in, gelu -> hidfrag ----
    {
        bf16x8 cb[4][2];
        #pragma unroll
        for (int dt = 0; dt < 4; ++dt)
            #pragma unroll
            for (int ks = 0; ks < 2; ++ks)
                cb[dt][ks] = *(const bf16x8*)&combfrag[dt][ks][l][0];
        float dmv[4];
        #pragma unroll
        for (int dt = 0; dt < 4; ++dt) {
            int m = mask[base + 16 * dt + li];
            dmv[dt] = m ? dist[base + 16 * dt + li] : 0.0f;
        }
        #pragma unroll
        for (int hp = 0; hp < 2; ++hp) {          // own k-tile: kt = 2w+hp
            u16x8 pend[4];
            #pragma unroll
            for (int b = 0; b < 2; ++b) {
                const int ht = 4 * w + 2 * hp + b;
                bf16x8 af0 = *(const bf16x8*)(ws + WIN_OFF + ((size_t)(0 * 16 + ht) * 64 + l) * 8);
                bf16x8 af1 = *(const bf16x8*)(ws + WIN_OFF + ((size_t)(1 * 16 + ht) * 64 + l) * 8);
                f32x4 w64v = *(const f32x4*)&w_in[64 * 256 + 16 * ht + 4 * g];
                f32x4 binv = *(const f32x4*)&b_in[16 * ht + 4 * g];
                #pragma unroll
                for (int dt = 0; dt < 4; ++dt) {
                    f32x4 acc;
                    #pragma unroll
                    for (int p = 0; p < 4; ++p)
                        acc[p] = __builtin_fmaf(dmv[dt], w64v[p], binv[p]);
                    acc = mfma16(af0, cb[dt][0], acc);
                    acc = mfma16(af1, cb[dt][1], acc);
                    #pragma unroll
                    for (int p = 0; p < 4; ++p)
                        pend[dt][4 * b + p] = to_bf16u(gelu_fast(acc[p]));
                }
            }
            #pragma unroll
            for (int dt = 0; dt < 4; ++dt)
                *(u16x8*)&hidfrag[dt][2 * w + hp][l][0] = pend[dt];
        }
    }
    __syncthreads();

    // ---- P2: score partials (wave w -> attn-hidden cols 16w..16w+15), B-frags preloaded ----
    {
        bf16x8 ba[8];
        #pragma unroll
        for (int kt = 0; kt < 8; ++kt)
            ba[kt] = *(const bf16x8*)(ws + WA1_OFF + ((size_t)(kt * 4 + w) * 64 + l) * 8);
        f32x4 acc2[4];
        #pragma unroll
        for (int rt = 0; rt < 4; ++rt) acc2[rt] = (f32x4){0.f, 0.f, 0.f, 0.f};
        #pragma unroll
        for (int kt = 0; kt < 8; ++kt) {
            #pragma unroll
            for (int rt = 0; rt < 4; ++rt) {
                bf16x8 a = *(const bf16x8*)&hidfrag[rt][kt][l][0];
                acc2[rt] = mfma16(a, ba[kt], acc2[rt]);
            }
        }
        const float ba1 = b_a1[16 * w + li];
        const float wa2 = w_a2[16 * w + li];
        #pragma unroll
        for (int rt = 0; rt < 4; ++rt) {
            float s[4];
            #pragma unroll
            for (int p = 0; p < 4; ++p) s[p] = gelu_fast(acc2[rt][p] + ba1) * wa2;
            #pragma unroll
            for (int off = 1; off <= 8; off <<= 1)
                #pragma unroll
                for (int p = 0; p < 4; ++p) s[p] += __shfl_xor(s[p], off, 64);
            if (li == 0) {
                f32x4 sv; sv[0] = s[0]; sv[1] = s[1]; sv[2] = s[2]; sv[3] = s[3];
                *(f32x4*)&scorep[w * 64 + 16 * rt + 4 * g] = sv;
            }
        }
    }
    __syncthreads();

    // ---- P3: softmax, redundant per wave (no extra barrier) ----
    {
        const int m = mask[base + l];
        float sc = scorep[l] + scorep[64 + l] + scorep[128 + l] + scorep[192 + l] + b_a2[0];
        if (!m) sc = -10000.0f;
        float mx = sc;
        #pragma unroll
        for (int off = 32; off; off >>= 1) mx = fmaxf(mx, __shfl_xor(mx, off, 64));
        float p = __expf(sc - mx);
        float sm = p;
        #pragma unroll
        for (int off = 32; off; off >>= 1) sm += __shfl_xor(sm, off, 64);
        attn_s[w * 64 + l] = p / sm;
    }
    // same-wave LDS RAW -> ordered by lgkmcnt, no __syncthreads needed

    // ---- P4: r[c] = sum_d attn[d]*gelu(hid@w_v1 + b_v1)[d][c]  (wave w -> cols 64w..) ----
    // ct in 2 passes of 2 to cap live accumulators at 32 (no spill); clustered loads.
    {
        f32x4 av[4];
        #pragma unroll
        for (int rt = 0; rt < 4; ++rt) av[rt] = *(const f32x4*)&attn_s[w * 64 + 16 * rt + 4 * g];
        #pragma unroll
        for (int half = 0; half < 2; ++half) {
            f32x4 acc3[2][4];   // [c2][rt]
            #pragma unroll
            for (int c2 = 0; c2 < 2; ++c2)
                #pragma unroll
                for (int rt = 0; rt < 4; ++rt) acc3[c2][rt] = (f32x4){0.f, 0.f, 0.f, 0.f};
            #pragma unroll
            for (int kt = 0; kt < 8; ++kt) {
                bf16x8 b0 = *(const bf16x8*)(ws + WV1_OFF + ((size_t)(kt * 16 + 4 * w + 2 * half + 0) * 64 + l) * 8);
                bf16x8 b1 = *(const bf16x8*)(ws + WV1_OFF + ((size_t)(kt * 16 + 4 * w + 2 * half + 1) * 64 + l) * 8);
                bf16x8 a[4];
                #pragma unroll
                for (int rt = 0; rt < 4; ++rt) a[rt] = *(const bf16x8*)&hidfrag[rt][kt][l][0];
                #pragma unroll
                for (int rt = 0; rt < 4; ++rt) {
                    acc3[0][rt] = mfma16(a[rt], b0, acc3[0][rt]);
                    acc3[1][rt] = mfma16(a[rt], b1, acc3[1][rt]);
                }
            }
            #pragma unroll
            for (int c2 = 0; c2 < 2; ++c2) {
                const int ct = 2 * half + c2;
                const int c = 64 * w + 16 * ct + li;
                const float bv = b_v1[c];
                float val = 0.f;
                #pragma unroll
                for (int rt = 0; rt < 4; ++rt)
                    #pragma unroll
                    for (int p = 0; p < 4; ++p)
                        val += av[rt][p] * gelu_fast(acc3[c2][rt][p] + bv);
                val += __shfl_xor(val, 16, 64);
                val += __shfl_xor(val, 32, 64);
                if (g == 0) r_bf[c] = to_bf16u(val);
            }
        }
    }
    __syncthreads();

    // ---- P5: out = r @ w_v2 via MFMA (r broadcast to all 16 A-rows), full K per wave ----
    {
        const int anyv = __any(mask[base + l] != 0);
        f32x4 acc[4];
        #pragma unroll
        for (int ct = 0; ct < 4; ++ct) acc[ct] = (f32x4){0.f, 0.f, 0.f, 0.f};
        #pragma unroll
        for (int kt = 0; kt < 8; ++kt) {
            bf16x8 a = *(const bf16x8*)&r_bf[kt * 32 + 8 * g];   // same for all li -> broadcast
            #pragma unroll
            for (int ct = 0; ct < 4; ++ct) {
                bf16x8 b = *(const bf16x8*)(ws + WV2_OFF + ((size_t)(kt * 16 + 4 * w + ct) * 64 + l) * 8);
                acc[ct] = mfma16(a, b, acc[ct]);
            }
        }
        if (g == 0) {
            #pragma unroll
            for (int ct = 0; ct < 4; ++ct) {
                const int c = 16 * (4 * w + ct) + li;
                float o = acc[ct][0] + b_v2[c];
                if (!anyv) o = fb[c];
                out[(size_t)blk * HH + c] = o;
            }
        }
    }
}

extern "C" void kernel_launch(void* const* d_in, const int* in_sizes, int n_in,
                              void* d_out, int out_size, void* d_ws, size_t ws_size,
                              hipStream_t stream) {
    const int*   a1    = (const int*)  d_in[0];
    const int*   a2    = (const int*)  d_in[1];
    const float* dist  = (const float*)d_in[2];
    const int*   mask  = (const int*)  d_in[3];
    const float* table = (const float*)d_in[4];
    const float* w_in  = (const float*)d_in[5];
    const float* b_in  = (const float*)d_in[6];
    const float* w_a1  = (const float*)d_in[7];
    const float* b_a1  = (const float*)d_in[8];
    const float* w_a2  = (const float*)d_in[9];
    const float* b_a2  = (const float*)d_in[10];
    const float* w_v1  = (const float*)d_in[11];
    const float* b_v1  = (const float*)d_in[12];
    const float* w_v2  = (const float*)d_in[13];
    const float* b_v2  = (const float*)d_in[14];
    const float* fb    = (const float*)d_in[15];
    float* out = (float*)d_out;
    unsigned short* ws = (unsigned short*)d_ws;

    pack_weights<<<80, 256, 0, stream>>>(w_in, w_a1, w_v1, w_v2, ws);
    dist_attn_kernel<<<BW, 256, 0, stream>>>(a1, a2, dist, mask, table,
                                             w_in, b_in, b_a1, w_a2, b_a2,
                                             b_v1, b_v2, fb, ws, out);
}